// Round 16
// baseline (1090.661 us; speedup 1.0000x reference)
//
#include <hip/hip_runtime.h>

#define GD(x,y) (((x)+(y)-1)/(y))

#define SH    10               // rows per bucket = 1024
#define BPR   (1 << SH)
#define BS    256
#define KSPL  24               // spmm splits per bucket
#define CAPSH 15               // slot capacity per bucket = 32768 edges
#define CAP   (1 << CAPSH)
#define CHUNK 2048             // edges per fill block (16KB staged LDS)

// init: cursor[b] = b*CAP (slot bases) + zero tickets + softmax(alpha)
__global__ void init_k(int* __restrict__ cursor, int* __restrict__ tick, int NBK,
                       const float* __restrict__ alpha, float* __restrict__ a, int na){
    int t = threadIdx.x;
    if (t < NBK) cursor[t] = t << CAPSH;
    if (t < 384) tick[t] = 0;              // 3 layers x 128 buckets
    if (t == 0){
        float m = alpha[0];
        for (int i = 1; i < na; ++i) m = fmaxf(m, alpha[i]);
        float s = 0.f;
        for (int i = 0; i < na; ++i){ float e = expf(alpha[i] - m); a[i] = e; s += e; }
        float inv = 1.f / s;
        for (int i = 0; i < na; ++i) a[i] *= inv;
    }
}

// fused heterogeneous kernel:
//   blocks [0, GF)      : LDS-staged bucket sort of a 2048-edge chunk
//                         (per-wave histograms + cursors: no cross-wave LDS contention)
//   blocks [GF, GF+GP)  : proj  y[n] = emb[idx[n]] @ W; out[n] = b + a0*y[n]
__global__ void fillproj_k(const int* __restrict__ row, const int* __restrict__ col,
                           const float* __restrict__ val, int* __restrict__ cursor,
                           int2* __restrict__ sep, int E, int NBK, int GF,
                           const float* __restrict__ emb, const int* __restrict__ idx,
                           const float* __restrict__ W, const float* __restrict__ bb,
                           const float* __restrict__ a, float* __restrict__ y,
                           float* __restrict__ out, int N){
    if (blockIdx.x < GF){
        __shared__ int2 staged[CHUNK];          // 16 KB
        __shared__ unsigned char bid[CHUNK];    // 2 KB
        __shared__ int h4[4 * 128];             // per-wave hist -> per-wave cursors
        __shared__ int sc[128], lstart[128], gbase[128];
        int t = threadIdx.x;
        int wv = t >> 6;
        int s = blockIdx.x * CHUNK;
        int e = min(E, s + CHUNK);
        int cnt = e - s;
        if (t < 128){ h4[t] = 0; h4[128+t] = 0; h4[256+t] = 0; h4[384+t] = 0; }
        __syncthreads();
        // pass 1: count (4-wide) into per-wave histogram
        int* hw = h4 + wv * 128;
        for (int base = s + t * 4; base < e; base += BS * 4){
            if (base + 3 < e){
                int4 r4 = *(const int4*)(row + base);
                atomicAdd(&hw[r4.x >> SH], 1);
                atomicAdd(&hw[r4.y >> SH], 1);
                atomicAdd(&hw[r4.z >> SH], 1);
                atomicAdd(&hw[r4.w >> SH], 1);
            } else {
                for (int j = 0; j < 4 && base + j < e; ++j)
                    atomicAdd(&hw[row[base + j] >> SH], 1);
            }
        }
        __syncthreads();
        int c0 = 0, c1 = 0, c2 = 0, tot = 0;
        if (t < 128){
            c0 = h4[t]; c1 = h4[128 + t]; c2 = h4[256 + t];
            tot = c0 + c1 + c2 + h4[384 + t];
            sc[t] = tot;
        }
        __syncthreads();
        // parallel exclusive scan over 128 bins (Hillis-Steele)
        #pragma unroll
        for (int off = 1; off < 128; off <<= 1){
            int add = (t < 128 && t >= off) ? sc[t - off] : 0;
            __syncthreads();
            if (t < 128) sc[t] += add;
            __syncthreads();
        }
        if (t < 128){
            int excl = sc[t] - tot;
            lstart[t] = excl;
            gbase[t]  = (tot > 0) ? atomicAdd(&cursor[t], tot) : 0;
            h4[t]       = excl;                 // wave-0 cursor
            h4[128 + t] = excl + c0;            // wave-1 cursor
            h4[256 + t] = excl + c0 + c1;       // wave-2 cursor
            h4[384 + t] = excl + c0 + c1 + c2;  // wave-3 cursor
        }
        __syncthreads();
        // pass 2: scatter into LDS (bucket-sorted within block), per-wave cursors
        int* lcw = h4 + wv * 128;
        for (int base = s + t * 4; base < e; base += BS * 4){
            int r[4]; int c[4]; float vv[4];
            int m = min(4, e - base);
            if (m == 4){
                int4 r4 = *(const int4*)(row + base);
                int4 c4 = *(const int4*)(col + base);
                float4 v4 = *(const float4*)(val + base);
                r[0]=r4.x; r[1]=r4.y; r[2]=r4.z; r[3]=r4.w;
                c[0]=c4.x; c[1]=c4.y; c[2]=c4.z; c[3]=c4.w;
                vv[0]=v4.x; vv[1]=v4.y; vv[2]=v4.z; vv[3]=v4.w;
            } else {
                for (int j = 0; j < m; ++j){ r[j]=row[base+j]; c[j]=col[base+j]; vv[j]=val[base+j]; }
            }
            for (int j = 0; j < m; ++j){
                int b = r[j] >> SH;
                int lp = atomicAdd(&lcw[b], 1);
                int2 pk;
                pk.x = c[j] | ((r[j] & (BPR - 1)) << 17);
                pk.y = __float_as_int(vv[j]);
                staged[lp] = pk;
                bid[lp] = (unsigned char)b;
            }
        }
        __syncthreads();
        // stream out: consecutive idx -> consecutive global positions per run
        for (int i2 = t; i2 < cnt; i2 += BS){
            int b = bid[i2];
            sep[gbase[b] + (i2 - lstart[b])] = staged[i2];
        }
    } else {
        int gt = (blockIdx.x - GF) * BS + threadIdx.x;
        int w = gt >> 6;
        int lane = gt & 63;
        int n = w * 2 + (lane >> 5);
        if (n >= N) return;
        int sl = lane & 31;
        float4 x = ((const float4*)(emb + (size_t)idx[n] * 128))[sl];
        int d0 = 4 * sl;
        float s0 = x.x * W[d0*2]   + x.y * W[d0*2+2] + x.z * W[d0*2+4] + x.w * W[d0*2+6];
        float s1 = x.x * W[d0*2+1] + x.y * W[d0*2+3] + x.z * W[d0*2+5] + x.w * W[d0*2+7];
        #pragma unroll
        for (int off = 16; off; off >>= 1){
            s0 += __shfl_down(s0, off, 32);
            s1 += __shfl_down(s1, off, 32);
        }
        if (sl == 0){
            float c = a[0];
            ((float2*)y)[n]   = make_float2(s0, s1);
            ((float2*)out)[n] = make_float2(bb[0] + c * s0, bb[1] + c * s1);
        }
    }
}

// split-bucket push SpMM with fused ticket-based combine:
// KSPL blocks per 1024-row bucket accumulate in private LDS, store partials,
// and the last-arriving block reduces all KSPL partials -> ynext, out.
__global__ void spmm_k(const int* __restrict__ cursor, const int2* __restrict__ sep,
                       const float* __restrict__ yin, float* __restrict__ partial,
                       int* __restrict__ tick, const float* __restrict__ a, int ai,
                       float* __restrict__ ynext, float* __restrict__ out,
                       int N, int NBK){
    __shared__ float accx[BPR];
    __shared__ float accy[BPR];
    __shared__ int lastf;
    int b  = blockIdx.x / KSPL;
    int sp = blockIdx.x % KSPL;
    int t  = threadIdx.x;
    for (int j = t; j < BPR; j += BS){ accx[j] = 0.f; accy[j] = 0.f; }
    __syncthreads();
    int s = b << CAPSH;
    int e = cursor[b];
    int len = e - s, per = GD(len, KSPL);
    int cs = s + sp * per, ce = min(e, cs + per);
    int i = cs + t;
    for (; i + 3 * BS < ce; i += 4 * BS){
        int2 p0 = sep[i], p1 = sep[i + BS], p2 = sep[i + 2*BS], p3 = sep[i + 3*BS];
        float2 m0 = ((const float2*)yin)[p0.x & 0x1FFFF];
        float2 m1 = ((const float2*)yin)[p1.x & 0x1FFFF];
        float2 m2 = ((const float2*)yin)[p2.x & 0x1FFFF];
        float2 m3 = ((const float2*)yin)[p3.x & 0x1FFFF];
        float v0 = __int_as_float(p0.y), v1 = __int_as_float(p1.y);
        float v2 = __int_as_float(p2.y), v3 = __int_as_float(p3.y);
        atomicAdd(&accx[p0.x >> 17], v0 * m0.x); atomicAdd(&accy[p0.x >> 17], v0 * m0.y);
        atomicAdd(&accx[p1.x >> 17], v1 * m1.x); atomicAdd(&accy[p1.x >> 17], v1 * m1.y);
        atomicAdd(&accx[p2.x >> 17], v2 * m2.x); atomicAdd(&accy[p2.x >> 17], v2 * m2.y);
        atomicAdd(&accx[p3.x >> 17], v3 * m3.x); atomicAdd(&accy[p3.x >> 17], v3 * m3.y);
    }
    for (; i < ce; i += BS){
        int2 pk = sep[i];
        float v = __int_as_float(pk.y);
        float2 m = ((const float2*)yin)[pk.x & 0x1FFFF];
        atomicAdd(&accx[pk.x >> 17], v * m.x);
        atomicAdd(&accy[pk.x >> 17], v * m.y);
    }
    __syncthreads();
    float2* dst = (float2*)partial + (size_t)(b * KSPL + sp) * BPR;
    for (int j = t; j < BPR; j += BS)
        dst[j] = make_float2(accx[j], accy[j]);
    // ticket: last arriver combines
    __threadfence();
    __syncthreads();
    if (t == 0){
        int old = __hip_atomic_fetch_add(&tick[b], 1, __ATOMIC_ACQ_REL,
                                         __HIP_MEMORY_SCOPE_AGENT);
        lastf = (old == KSPL - 1) ? 1 : 0;
    }
    __syncthreads();
    if (!lastf) return;
    __threadfence();
    float c = a[ai];
    const float2* pb = (const float2*)partial + (size_t)b * KSPL * BPR;
    for (int j = t; j < BPR; j += BS){
        int n = (b << SH) + j;
        if (n < N){
            float sx = 0.f, sy = 0.f;
            #pragma unroll
            for (int sp2 = 0; sp2 < KSPL; ++sp2){
                float2 v = pb[(size_t)sp2 * BPR + j];
                sx += v.x; sy += v.y;
            }
            ((float2*)ynext)[n] = make_float2(sx, sy);
            float2 o = ((float2*)out)[n];
            o.x += c * sx; o.y += c * sy;
            ((float2*)out)[n] = o;
        }
    }
}

extern "C" void kernel_launch(void* const* d_in, const int* in_sizes, int n_in,
                              void* d_out, int out_size, void* d_ws, size_t ws_size,
                              hipStream_t stream) {
    const int*   node_idx = (const int*)  d_in[0];
    const int*   adj_row  = (const int*)  d_in[1];
    const int*   adj_col  = (const int*)  d_in[2];
    const float* adj_val  = (const float*)d_in[3];
    const float* emb      = (const float*)d_in[4];
    const float* alpha    = (const float*)d_in[5];
    const float* W        = (const float*)d_in[6];
    const float* b        = (const float*)d_in[7];
    float* out = (float*)d_out;

    const int N = in_sizes[0];      // 100000
    const int E = in_sizes[1];      // 1600000
    const int L = in_sizes[5] - 1;  // 3
    const int NBK = GD(N, BPR);     // 98 buckets
    const int GF  = GD(E, CHUNK);   // 782 fill blocks
    const int GP  = GD(N * 32, BS); // 12500 proj blocks

    // workspace
    char* w = (char*)d_ws;
    float* yA     = (float*)w;  w += (size_t)N * 2 * 4;
    float* yB     = (float*)w;  w += (size_t)N * 2 * 4;
    float* partial= (float*)w;  w += (size_t)NBK * KSPL * BPR * 2 * 4;  // 19.3 MB
    int2*  sep    = (int2*)w;   w += (size_t)NBK * CAP * 8;             // 25.7 MB
    int*   cursor = (int*)w;    w += 1024;
    int*   tick   = (int*)w;    w += 3 * 128 * 4;
    float* a      = (float*)w;

    // cursor slot bases + ticket zero + softmax(alpha)
    init_k<<<1, 512, 0, stream>>>(cursor, tick, NBK, alpha, a, L + 1);

    // fused: bucket sort of edges  ||  projection to 2 dims + out init
    fillproj_k<<<GF + GP, BS, 0, stream>>>(adj_row, adj_col, adj_val, cursor, sep,
                                           E, NBK, GF, emb, node_idx, W, b, a,
                                           yA, out, N);

    // propagation layers: split-bucket SpMM with fused ticket combine
    float* ysrc = yA;
    float* ydst = yB;
    for (int i = 0; i < L; ++i){
        spmm_k<<<NBK * KSPL, BS, 0, stream>>>(cursor, sep, ysrc, partial,
                                              tick + i * 128, a, i + 1,
                                              ydst, out, N, NBK);
        float* tmp = ysrc; ysrc = ydst; ydst = tmp;
    }
}

// Round 17
// 148.762 us; speedup vs baseline: 7.3316x; 7.3316x over previous
//
#include <hip/hip_runtime.h>

#define GD(x,y) (((x)+(y)-1)/(y))

#define SH    7                // rows per bucket = 128 (fine: exclusive spmm ownership)
#define BPR   (1 << SH)
#define BS    256
#define CAPSH 12               // slot capacity per bucket = 4096 edges (avg ~2047)
#define CHUNK 4096             // edges per fill block (32KB staged LDS)
#define MAXB  800              // static LDS bound on bucket count (N <= 102400)

// init: cursor[b] = b*CAP (slot bases) + softmax(alpha)
__global__ void init_k(int* __restrict__ cursor, int NBK,
                       const float* __restrict__ alpha, float* __restrict__ a, int na){
    int t = threadIdx.x;
    if (t < NBK) cursor[t] = t << CAPSH;
    if (t == 0){
        float m = alpha[0];
        for (int i = 1; i < na; ++i) m = fmaxf(m, alpha[i]);
        float s = 0.f;
        for (int i = 0; i < na; ++i){ float e = expf(alpha[i] - m); a[i] = e; s += e; }
        float inv = 1.f / s;
        for (int i = 0; i < na; ++i) a[i] *= inv;
    }
}

// fused heterogeneous kernel:
//   blocks [0, GF)      : LDS-staged 782-bucket sort of a 4096-edge chunk
//                         (per-wave histograms/cursors; pack {col | rloc7<<17, val})
//   blocks [GF, GF+GP)  : proj  y[n] = emb[idx[n]] @ W; out[n] = b + a0*y[n]
__global__ void fillproj_k(const int* __restrict__ row, const int* __restrict__ col,
                           const float* __restrict__ val, int* __restrict__ cursor,
                           int2* __restrict__ sep, int E, int NBK, int GF,
                           const float* __restrict__ emb, const int* __restrict__ idx,
                           const float* __restrict__ W, const float* __restrict__ bb,
                           const float* __restrict__ a, float* __restrict__ y,
                           float* __restrict__ out, int N){
    if (blockIdx.x < GF){
        __shared__ int2 staged[CHUNK];           // 32 KB
        __shared__ unsigned short bid[CHUNK];    // 8 KB
        __shared__ int h4[4 * MAXB];             // per-wave hist -> per-wave cursors
        __shared__ int lstart[MAXB];
        __shared__ int gbase[MAXB];
        __shared__ int sc[BS];
        int t = threadIdx.x;
        int wv = t >> 6;
        int s = blockIdx.x * CHUNK;
        int e = min(E, s + CHUNK);
        int cnt = e - s;
        for (int i = t; i < 4 * MAXB; i += BS) h4[i] = 0;
        __syncthreads();
        // pass 1: count (4-wide) into per-wave histogram
        int* hw = h4 + wv * MAXB;
        for (int base = s + t * 4; base < e; base += BS * 4){
            if (base + 3 < e){
                int4 r4 = *(const int4*)(row + base);
                atomicAdd(&hw[r4.x >> SH], 1);
                atomicAdd(&hw[r4.y >> SH], 1);
                atomicAdd(&hw[r4.z >> SH], 1);
                atomicAdd(&hw[r4.w >> SH], 1);
            } else {
                for (int j = 0; j < 4 && base + j < e; ++j)
                    atomicAdd(&hw[row[base + j] >> SH], 1);
            }
        }
        __syncthreads();
        // per-thread 4-bin totals -> 256-wide scan -> per-bin layout + reservations
        int b0 = t * 4;
        int tt0=0, tt1=0, tt2=0, tt3=0, tsum;
        if (b0     < NBK) tt0 = h4[b0]     + h4[MAXB+b0]     + h4[2*MAXB+b0]     + h4[3*MAXB+b0];
        if (b0 + 1 < NBK) tt1 = h4[b0+1]   + h4[MAXB+b0+1]   + h4[2*MAXB+b0+1]   + h4[3*MAXB+b0+1];
        if (b0 + 2 < NBK) tt2 = h4[b0+2]   + h4[MAXB+b0+2]   + h4[2*MAXB+b0+2]   + h4[3*MAXB+b0+2];
        if (b0 + 3 < NBK) tt3 = h4[b0+3]   + h4[MAXB+b0+3]   + h4[2*MAXB+b0+3]   + h4[3*MAXB+b0+3];
        tsum = tt0 + tt1 + tt2 + tt3;
        sc[t] = tsum;
        __syncthreads();
        #pragma unroll
        for (int off = 1; off < BS; off <<= 1){
            int add = (t >= off) ? sc[t - off] : 0;
            __syncthreads();
            sc[t] += add;
            __syncthreads();
        }
        int run = sc[t] - tsum;
        #pragma unroll
        for (int j = 0; j < 4; ++j){
            int bin = b0 + j;
            int tj = (j == 0) ? tt0 : (j == 1) ? tt1 : (j == 2) ? tt2 : tt3;
            if (bin < NBK){
                int c0 = h4[bin], c1 = h4[MAXB+bin], c2 = h4[2*MAXB+bin];
                lstart[bin] = run;
                gbase[bin]  = (tj > 0) ? atomicAdd(&cursor[bin], tj) : 0;
                h4[bin]          = run;
                h4[MAXB+bin]     = run + c0;
                h4[2*MAXB+bin]   = run + c0 + c1;
                h4[3*MAXB+bin]   = run + c0 + c1 + c2;
                run += tj;
            }
        }
        __syncthreads();
        // pass 2: scatter into LDS (bucket-sorted within block), per-wave cursors
        int* lcw = h4 + wv * MAXB;
        for (int base = s + t * 4; base < e; base += BS * 4){
            int r[4]; int c[4]; float vv[4];
            int m = min(4, e - base);
            if (m == 4){
                int4 r4 = *(const int4*)(row + base);
                int4 c4 = *(const int4*)(col + base);
                float4 v4 = *(const float4*)(val + base);
                r[0]=r4.x; r[1]=r4.y; r[2]=r4.z; r[3]=r4.w;
                c[0]=c4.x; c[1]=c4.y; c[2]=c4.z; c[3]=c4.w;
                vv[0]=v4.x; vv[1]=v4.y; vv[2]=v4.z; vv[3]=v4.w;
            } else {
                for (int j = 0; j < m; ++j){ r[j]=row[base+j]; c[j]=col[base+j]; vv[j]=val[base+j]; }
            }
            for (int j = 0; j < m; ++j){
                int b = r[j] >> SH;
                int lp = atomicAdd(&lcw[b], 1);
                int2 pk;
                pk.x = c[j] | ((r[j] & (BPR - 1)) << 17);
                pk.y = __float_as_int(vv[j]);
                staged[lp] = pk;
                bid[lp] = (unsigned short)b;
            }
        }
        __syncthreads();
        // stream out: consecutive idx -> consecutive global positions per run
        for (int i2 = t; i2 < cnt; i2 += BS){
            int b = bid[i2];
            sep[gbase[b] + (i2 - lstart[b])] = staged[i2];
        }
    } else {
        int gt = (blockIdx.x - GF) * BS + threadIdx.x;
        int w = gt >> 6;
        int lane = gt & 63;
        int n = w * 2 + (lane >> 5);
        if (n >= N) return;
        int sl = lane & 31;
        float4 x = ((const float4*)(emb + (size_t)idx[n] * 128))[sl];
        int d0 = 4 * sl;
        float s0 = x.x * W[d0*2]   + x.y * W[d0*2+2] + x.z * W[d0*2+4] + x.w * W[d0*2+6];
        float s1 = x.x * W[d0*2+1] + x.y * W[d0*2+3] + x.z * W[d0*2+5] + x.w * W[d0*2+7];
        #pragma unroll
        for (int off = 16; off; off >>= 1){
            s0 += __shfl_down(s0, off, 32);
            s1 += __shfl_down(s1, off, 32);
        }
        if (sl == 0){
            float c = a[0];
            ((float2*)y)[n]   = make_float2(s0, s1);
            ((float2*)out)[n] = make_float2(bb[0] + c * s0, bb[1] + c * s1);
        }
    }
}

// fine-bucket push SpMM: one block per 128-row bucket, 1KB LDS accumulator,
// EXCLUSIVE row ownership -> direct non-atomic writeback (no partials, no combine).
__global__ void spmm_k(const int* __restrict__ cursor, const int2* __restrict__ sep,
                       const float* __restrict__ yin, float* __restrict__ ynext,
                       const float* __restrict__ a, int ai, float* __restrict__ out,
                       int N, int store){
    __shared__ float accx[BPR];
    __shared__ float accy[BPR];
    int sb = blockIdx.x;
    int t  = threadIdx.x;
    if (t < BPR){ accx[t] = 0.f; accy[t] = 0.f; }
    __syncthreads();
    int s = sb << CAPSH;
    int e = cursor[sb];
    int i = s + t;
    for (; i + 3 * BS < e; i += 4 * BS){
        int2 p0 = sep[i], p1 = sep[i + BS], p2 = sep[i + 2*BS], p3 = sep[i + 3*BS];
        float2 m0 = ((const float2*)yin)[p0.x & 0x1FFFF];
        float2 m1 = ((const float2*)yin)[p1.x & 0x1FFFF];
        float2 m2 = ((const float2*)yin)[p2.x & 0x1FFFF];
        float2 m3 = ((const float2*)yin)[p3.x & 0x1FFFF];
        float v0 = __int_as_float(p0.y), v1 = __int_as_float(p1.y);
        float v2 = __int_as_float(p2.y), v3 = __int_as_float(p3.y);
        atomicAdd(&accx[p0.x >> 17], v0 * m0.x); atomicAdd(&accy[p0.x >> 17], v0 * m0.y);
        atomicAdd(&accx[p1.x >> 17], v1 * m1.x); atomicAdd(&accy[p1.x >> 17], v1 * m1.y);
        atomicAdd(&accx[p2.x >> 17], v2 * m2.x); atomicAdd(&accy[p2.x >> 17], v2 * m2.y);
        atomicAdd(&accx[p3.x >> 17], v3 * m3.x); atomicAdd(&accy[p3.x >> 17], v3 * m3.y);
    }
    for (; i < e; i += BS){
        int2 pk = sep[i];
        float v = __int_as_float(pk.y);
        float2 m = ((const float2*)yin)[pk.x & 0x1FFFF];
        atomicAdd(&accx[pk.x >> 17], v * m.x);
        atomicAdd(&accy[pk.x >> 17], v * m.y);
    }
    __syncthreads();
    if (t < BPR){
        int n = (sb << SH) + t;
        if (n < N){
            float2 z = make_float2(accx[t], accy[t]);
            if (store) ((float2*)ynext)[n] = z;
            float c = a[ai];
            float2 o = ((float2*)out)[n];
            o.x += c * z.x; o.y += c * z.y;
            ((float2*)out)[n] = o;
        }
    }
}

extern "C" void kernel_launch(void* const* d_in, const int* in_sizes, int n_in,
                              void* d_out, int out_size, void* d_ws, size_t ws_size,
                              hipStream_t stream) {
    const int*   node_idx = (const int*)  d_in[0];
    const int*   adj_row  = (const int*)  d_in[1];
    const int*   adj_col  = (const int*)  d_in[2];
    const float* adj_val  = (const float*)d_in[3];
    const float* emb      = (const float*)d_in[4];
    const float* alpha    = (const float*)d_in[5];
    const float* W        = (const float*)d_in[6];
    const float* b        = (const float*)d_in[7];
    float* out = (float*)d_out;

    const int N = in_sizes[0];      // 100000
    const int E = in_sizes[1];      // 1600000
    const int L = in_sizes[5] - 1;  // 3
    const int NBK = GD(N, BPR);     // 782 fine buckets (<= MAXB)
    const int GF  = GD(E, CHUNK);   // 391 fill blocks
    const int GP  = GD(N * 32, BS); // 12500 proj blocks

    // workspace
    char* w = (char*)d_ws;
    float* yA     = (float*)w;  w += (size_t)N * 2 * 4;
    float* yB     = (float*)w;  w += (size_t)N * 2 * 4;
    int2*  sep    = (int2*)w;   w += ((size_t)NBK << CAPSH) * 8;   // 25.6 MB
    int*   cursor = (int*)w;    w += (size_t)MAXB * 4 + 1024;
    float* a      = (float*)w;

    // cursor slot bases + softmax(alpha)
    init_k<<<1, 1024, 0, stream>>>(cursor, NBK, alpha, a, L + 1);

    // fused: fine bucket sort of edges  ||  projection to 2 dims + out init
    fillproj_k<<<GF + GP, BS, 0, stream>>>(adj_row, adj_col, adj_val, cursor, sep,
                                           E, NBK, GF, emb, node_idx, W, b, a,
                                           yA, out, N);

    // propagation layers: exclusive-ownership SpMM, direct writeback
    float* ysrc = yA;
    float* ydst = yB;
    for (int i = 0; i < L; ++i){
        spmm_k<<<NBK, BS, 0, stream>>>(cursor, sep, ysrc, ydst, a, i + 1,
                                       out, N, (i < L - 1) ? 1 : 0);
        float* tmp = ysrc; ysrc = ydst; ydst = tmp;
    }
}

// Round 18
// 117.122 us; speedup vs baseline: 9.3122x; 1.2701x over previous
//
#include <hip/hip_runtime.h>

#define GD(x,y) (((x)+(y)-1)/(y))

#define SH    10               // rows per bucket = 1024
#define BPR   (1 << SH)
#define BS    256
#define KSPL  16               // spmm splits per bucket
#define CAPSH 15               // slot capacity per bucket = 32768 edges
#define CAP   (1 << CAPSH)
#define CHUNK 4096             // edges per fill block (32KB staged LDS)

static __device__ __forceinline__ float2 ntload2(const float2* p){
    unsigned long long u = __builtin_nontemporal_load((const unsigned long long*)p);
    return *(float2*)&u;
}
static __device__ __forceinline__ void ntstore2(float2* p, float2 v){
    __builtin_nontemporal_store(*(unsigned long long*)&v, (unsigned long long*)p);
}

// init: cursor[b] = b*CAP (slot bases) + softmax(alpha)
__global__ void init_k(int* __restrict__ cursor, int NBK,
                       const float* __restrict__ alpha, float* __restrict__ a, int na){
    int t = threadIdx.x;
    if (t < NBK) cursor[t] = t << CAPSH;
    if (t == 0){
        float m = alpha[0];
        for (int i = 1; i < na; ++i) m = fmaxf(m, alpha[i]);
        float s = 0.f;
        for (int i = 0; i < na; ++i){ float e = expf(alpha[i] - m); a[i] = e; s += e; }
        float inv = 1.f / s;
        for (int i = 0; i < na; ++i) a[i] *= inv;
    }
}

// fused heterogeneous kernel:
//   blocks [0, GF)      : LDS-staged bucket sort of a 4096-edge chunk
//                         (per-wave histograms + cursors: no cross-wave LDS contention)
//   blocks [GF, GF+GP)  : proj  y[n] = emb[idx[n]] @ W; out[n] = b + a0*y[n]
__global__ void fillproj_k(const int* __restrict__ row, const int* __restrict__ col,
                           const float* __restrict__ val, int* __restrict__ cursor,
                           int2* __restrict__ sep, int E, int NBK, int GF,
                           const float* __restrict__ emb, const int* __restrict__ idx,
                           const float* __restrict__ W, const float* __restrict__ bb,
                           const float* __restrict__ a, float* __restrict__ y,
                           float* __restrict__ out, int N){
    if (blockIdx.x < GF){
        __shared__ int2 staged[CHUNK];          // 32 KB
        __shared__ unsigned char bid[CHUNK];    // 4 KB
        __shared__ int h4[4 * 128];             // per-wave hist -> per-wave cursors
        __shared__ int sc[128], lstart[128], gbase[128];
        int t = threadIdx.x;
        int wv = t >> 6;
        int s = blockIdx.x * CHUNK;
        int e = min(E, s + CHUNK);
        int cnt = e - s;
        if (t < 128){ h4[t] = 0; h4[128+t] = 0; h4[256+t] = 0; h4[384+t] = 0; }
        __syncthreads();
        // pass 1: count (4-wide) into per-wave histogram
        int* hw = h4 + wv * 128;
        for (int base = s + t * 4; base < e; base += BS * 4){
            if (base + 3 < e){
                int4 r4 = *(const int4*)(row + base);
                atomicAdd(&hw[r4.x >> SH], 1);
                atomicAdd(&hw[r4.y >> SH], 1);
                atomicAdd(&hw[r4.z >> SH], 1);
                atomicAdd(&hw[r4.w >> SH], 1);
            } else {
                for (int j = 0; j < 4 && base + j < e; ++j)
                    atomicAdd(&hw[row[base + j] >> SH], 1);
            }
        }
        __syncthreads();
        int c0 = 0, c1 = 0, c2 = 0, tot = 0;
        if (t < 128){
            c0 = h4[t]; c1 = h4[128 + t]; c2 = h4[256 + t];
            tot = c0 + c1 + c2 + h4[384 + t];
            sc[t] = tot;
        }
        __syncthreads();
        // parallel exclusive scan over 128 bins (Hillis-Steele)
        #pragma unroll
        for (int off = 1; off < 128; off <<= 1){
            int add = (t < 128 && t >= off) ? sc[t - off] : 0;
            __syncthreads();
            if (t < 128) sc[t] += add;
            __syncthreads();
        }
        if (t < 128){
            int excl = sc[t] - tot;
            lstart[t] = excl;
            gbase[t]  = (tot > 0) ? atomicAdd(&cursor[t], tot) : 0;
            h4[t]       = excl;                 // wave-0 cursor
            h4[128 + t] = excl + c0;            // wave-1 cursor
            h4[256 + t] = excl + c0 + c1;       // wave-2 cursor
            h4[384 + t] = excl + c0 + c1 + c2;  // wave-3 cursor
        }
        __syncthreads();
        // pass 2: scatter into LDS (bucket-sorted within block), per-wave cursors
        int* lcw = h4 + wv * 128;
        for (int base = s + t * 4; base < e; base += BS * 4){
            int r[4]; int c[4]; float vv[4];
            int m = min(4, e - base);
            if (m == 4){
                int4 r4 = *(const int4*)(row + base);
                int4 c4 = *(const int4*)(col + base);
                float4 v4 = *(const float4*)(val + base);
                r[0]=r4.x; r[1]=r4.y; r[2]=r4.z; r[3]=r4.w;
                c[0]=c4.x; c[1]=c4.y; c[2]=c4.z; c[3]=c4.w;
                vv[0]=v4.x; vv[1]=v4.y; vv[2]=v4.z; vv[3]=v4.w;
            } else {
                for (int j = 0; j < m; ++j){ r[j]=row[base+j]; c[j]=col[base+j]; vv[j]=val[base+j]; }
            }
            for (int j = 0; j < m; ++j){
                int b = r[j] >> SH;
                int lp = atomicAdd(&lcw[b], 1);
                int2 pk;
                pk.x = c[j] | ((r[j] & (BPR - 1)) << 17);
                pk.y = __float_as_int(vv[j]);
                staged[lp] = pk;
                bid[lp] = (unsigned char)b;
            }
        }
        __syncthreads();
        // stream out: consecutive idx -> consecutive global positions per run
        for (int i2 = t; i2 < cnt; i2 += BS){
            int b = bid[i2];
            sep[gbase[b] + (i2 - lstart[b])] = staged[i2];
        }
    } else {
        int gt = (blockIdx.x - GF) * BS + threadIdx.x;
        int w = gt >> 6;
        int lane = gt & 63;
        int n = w * 2 + (lane >> 5);
        if (n >= N) return;
        int sl = lane & 31;
        float4 x = ((const float4*)(emb + (size_t)idx[n] * 128))[sl];
        int d0 = 4 * sl;
        float s0 = x.x * W[d0*2]   + x.y * W[d0*2+2] + x.z * W[d0*2+4] + x.w * W[d0*2+6];
        float s1 = x.x * W[d0*2+1] + x.y * W[d0*2+3] + x.z * W[d0*2+5] + x.w * W[d0*2+7];
        #pragma unroll
        for (int off = 16; off; off >>= 1){
            s0 += __shfl_down(s0, off, 32);
            s1 += __shfl_down(s1, off, 32);
        }
        if (sl == 0){
            float c = a[0];
            ((float2*)y)[n]   = make_float2(s0, s1);
            ((float2*)out)[n] = make_float2(bb[0] + c * s0, bb[1] + c * s1);
        }
    }
}

// split-bucket push SpMM: KSPL blocks per 1024-row bucket, private LDS
// accumulator, nontemporal contiguous writeback of partials.
// Plain (cached) sep loads: sep is L3-resident on layers 2-3.
__global__ void spmm_k(const int* __restrict__ cursor, const int2* __restrict__ sep,
                       const float* __restrict__ yin, float* __restrict__ partial,
                       int NBK){
    __shared__ float accx[BPR];
    __shared__ float accy[BPR];
    int b  = blockIdx.x / KSPL;
    int sp = blockIdx.x % KSPL;
    int t  = threadIdx.x;
    for (int j = t; j < BPR; j += BS){ accx[j] = 0.f; accy[j] = 0.f; }
    __syncthreads();
    int s = b << CAPSH;
    int e = cursor[b];
    int len = e - s, per = GD(len, KSPL);
    int cs = s + sp * per, ce = min(e, cs + per);
    int i = cs + t;
    for (; i + 3 * BS < ce; i += 4 * BS){
        int2 p0 = sep[i], p1 = sep[i + BS], p2 = sep[i + 2*BS], p3 = sep[i + 3*BS];
        float2 m0 = ((const float2*)yin)[p0.x & 0x1FFFF];
        float2 m1 = ((const float2*)yin)[p1.x & 0x1FFFF];
        float2 m2 = ((const float2*)yin)[p2.x & 0x1FFFF];
        float2 m3 = ((const float2*)yin)[p3.x & 0x1FFFF];
        float v0 = __int_as_float(p0.y), v1 = __int_as_float(p1.y);
        float v2 = __int_as_float(p2.y), v3 = __int_as_float(p3.y);
        atomicAdd(&accx[p0.x >> 17], v0 * m0.x); atomicAdd(&accy[p0.x >> 17], v0 * m0.y);
        atomicAdd(&accx[p1.x >> 17], v1 * m1.x); atomicAdd(&accy[p1.x >> 17], v1 * m1.y);
        atomicAdd(&accx[p2.x >> 17], v2 * m2.x); atomicAdd(&accy[p2.x >> 17], v2 * m2.y);
        atomicAdd(&accx[p3.x >> 17], v3 * m3.x); atomicAdd(&accy[p3.x >> 17], v3 * m3.y);
    }
    for (; i < ce; i += BS){
        int2 pk = sep[i];
        float v = __int_as_float(pk.y);
        float2 m = ((const float2*)yin)[pk.x & 0x1FFFF];
        atomicAdd(&accx[pk.x >> 17], v * m.x);
        atomicAdd(&accy[pk.x >> 17], v * m.y);
    }
    __syncthreads();
    float2* dst = (float2*)partial + (size_t)(b * KSPL + sp) * BPR;
    for (int j = t; j < BPR; j += BS)
        ntstore2(&dst[j], make_float2(accx[j], accy[j]));
}

// combine partials: y_next[n] = sum_sp partial[b,sp,j]; out[n] += a[ai]*y_next.
__global__ void comb_k(const float* __restrict__ partial, const float* __restrict__ a,
                       int ai, float* __restrict__ ynext, float* __restrict__ out,
                       int N, int store){
    int n = blockIdx.x * blockDim.x + threadIdx.x;
    if (n >= N) return;
    int b = n >> SH, j = n & (BPR - 1);
    const float2* p = (const float2*)partial + (size_t)b * KSPL * BPR + j;
    float sx = 0.f, sy = 0.f;
    #pragma unroll
    for (int sp = 0; sp < KSPL; ++sp){
        float2 v = ntload2(&p[(size_t)sp * BPR]);
        sx += v.x; sy += v.y;
    }
    if (store) ((float2*)ynext)[n] = make_float2(sx, sy);
    float c = a[ai];
    float2 o = ((float2*)out)[n];
    o.x += c * sx; o.y += c * sy;
    ((float2*)out)[n] = o;
}

extern "C" void kernel_launch(void* const* d_in, const int* in_sizes, int n_in,
                              void* d_out, int out_size, void* d_ws, size_t ws_size,
                              hipStream_t stream) {
    const int*   node_idx = (const int*)  d_in[0];
    const int*   adj_row  = (const int*)  d_in[1];
    const int*   adj_col  = (const int*)  d_in[2];
    const float* adj_val  = (const float*)d_in[3];
    const float* emb      = (const float*)d_in[4];
    const float* alpha    = (const float*)d_in[5];
    const float* W        = (const float*)d_in[6];
    const float* b        = (const float*)d_in[7];
    float* out = (float*)d_out;

    const int N = in_sizes[0];      // 100000
    const int E = in_sizes[1];      // 1600000
    const int L = in_sizes[5] - 1;  // 3
    const int NBK = GD(N, BPR);     // 98 buckets
    const int GF  = GD(E, CHUNK);   // 391 fill blocks
    const int GP  = GD(N * 32, BS); // 12500 proj blocks

    // workspace
    char* w = (char*)d_ws;
    float* yA     = (float*)w;  w += (size_t)N * 2 * 4;
    float* yB     = (float*)w;  w += (size_t)N * 2 * 4;
    float* partial= (float*)w;  w += (size_t)NBK * KSPL * BPR * 2 * 4;  // 12.9 MB
    int2*  sep    = (int2*)w;   w += (size_t)NBK * CAP * 8;             // 25.7 MB
    int*   cursor = (int*)w;    w += 1024;
    float* a      = (float*)w;

    // cursor slot bases + softmax(alpha)
    init_k<<<1, 128, 0, stream>>>(cursor, NBK, alpha, a, L + 1);

    // fused: bucket sort of edges  ||  projection to 2 dims + out init
    fillproj_k<<<GF + GP, BS, 0, stream>>>(adj_row, adj_col, adj_val, cursor, sep,
                                           E, NBK, GF, emb, node_idx, W, b, a,
                                           yA, out, N);

    // propagation layers: split-bucket SpMM -> non-atomic combine
    float* ysrc = yA;
    float* ydst = yB;
    for (int i = 0; i < L; ++i){
        spmm_k<<<NBK * KSPL, BS, 0, stream>>>(cursor, sep, ysrc, partial, NBK);
        comb_k<<<GD(N, 256), 256, 0, stream>>>(partial, a, i + 1, ydst, out,
                                               N, (i < L - 1) ? 1 : 0);
        float* tmp = ysrc; ysrc = ydst; ydst = tmp;
    }
}